// Round 3
// baseline (173.443 us; speedup 1.0000x reference)
//
#include <hip/hip_runtime.h>
#include <math.h>

// WL1 loss over [B=16, C=3, H=512, W=512] fp32.
//   r = sum_c|hr-sr|/255 ; e = sum_c|hr-ema|/255
//   patch_w[b] = (unbiased var of r over sample)^0.2
//   pixel_w = unbiased 3x3 local var of r (reflect pad)
//   loss = mean(|w*sr - w*hr|) = (1/N) sum patch_w * pixel_w * mask * 255*r
//
// R3: register-streaming stencil, no LDS tiles, no barriers.
// Wave = 256 cols x 8-row strip; lane = 4 cols; 3 rolling rows of r in regs;
// horizontal halo via __shfl; wave-edge cols via 2-lane scalar loads;
// depth-2 row prefetch for continuous MLP. 2048 waves = 512 blocks.

#define BB 16
#define HH 512
#define WW 512
#define HW (HH * WW)
#define CHW (3 * HW)
#define STRIP 8
#define NSTRIPS (HH / STRIP)        // 64
#define REG_PER_B (2 * NSTRIPS)     // 128 regions per batch
#define NREGIONS (BB * REG_PER_B)   // 2048
#define NBLOCKS (NREGIONS / 4)      // 512 blocks x 256 threads

__device__ __forceinline__ int reflect_h(int gh) {
  gh = gh < 0 ? -gh : gh;
  return gh >= HH ? 2 * HH - 2 - gh : gh;
}

struct Row {
  float4 r;     // residual_sr for lane's 4 cols
  float4 e;     // residual_ema (valid only when loaded WITH_E)
  float lv, rv; // left/right neighbor r (cross-lane resolved at load)
};

template <bool WITH_E>
__device__ __forceinline__ Row load_row(const float* __restrict__ hrb,
                                        const float* __restrict__ srb,
                                        const float* __restrict__ emb, int n,
                                        int col, int wedge, bool edge_lane,
                                        int lane) {
  Row o;
  const int gh = reflect_h(n);
  const float* hp = hrb + gh * WW + col;
  const float* sp = srb + gh * WW + col;
  float4 h0 = *(const float4*)hp;
  float4 h1 = *(const float4*)(hp + HW);
  float4 h2 = *(const float4*)(hp + 2 * HW);
  float4 s0 = *(const float4*)sp;
  float4 s1 = *(const float4*)(sp + HW);
  float4 s2 = *(const float4*)(sp + 2 * HW);
  o.r.x = (fabsf(h0.x - s0.x) + fabsf(h1.x - s1.x) + fabsf(h2.x - s2.x)) / 255.0f;
  o.r.y = (fabsf(h0.y - s0.y) + fabsf(h1.y - s1.y) + fabsf(h2.y - s2.y)) / 255.0f;
  o.r.z = (fabsf(h0.z - s0.z) + fabsf(h1.z - s1.z) + fabsf(h2.z - s2.z)) / 255.0f;
  o.r.w = (fabsf(h0.w - s0.w) + fabsf(h1.w - s1.w) + fabsf(h2.w - s2.w)) / 255.0f;
  if (WITH_E) {
    const float* ep = emb + gh * WW + col;
    float4 e0 = *(const float4*)ep;
    float4 e1 = *(const float4*)(ep + HW);
    float4 e2 = *(const float4*)(ep + 2 * HW);
    o.e.x = (fabsf(h0.x - e0.x) + fabsf(h1.x - e1.x) + fabsf(h2.x - e2.x)) / 255.0f;
    o.e.y = (fabsf(h0.y - e0.y) + fabsf(h1.y - e1.y) + fabsf(h2.y - e2.y)) / 255.0f;
    o.e.z = (fabsf(h0.z - e0.z) + fabsf(h1.z - e1.z) + fabsf(h2.z - e2.z)) / 255.0f;
    o.e.w = (fabsf(h0.w - e0.w) + fabsf(h1.w - e1.w) + fabsf(h2.w - e2.w)) / 255.0f;
  } else {
    o.e = make_float4(0.f, 0.f, 0.f, 0.f);
  }
  float edge = 0.f;
  if (edge_lane) {
    const float* hq = hrb + gh * WW + wedge;
    const float* sq = srb + gh * WW + wedge;
    edge = (fabsf(hq[0] - sq[0]) + fabsf(hq[HW] - sq[HW]) +
            fabsf(hq[2 * HW] - sq[2 * HW])) /
           255.0f;
  }
  float lvs = __shfl_up(o.r.w, 1, 64);
  float rvs = __shfl_down(o.r.x, 1, 64);
  o.lv = (lane == 0) ? edge : lvs;
  o.rv = (lane == 63) ? edge : rvs;
  return o;
}

__device__ __forceinline__ void row6(const Row& R, float* v) {
  v[0] = R.lv; v[1] = R.r.x; v[2] = R.r.y; v[3] = R.r.z; v[4] = R.r.w; v[5] = R.rv;
}

__global__ __launch_bounds__(256) void wl1_main(
    const float* __restrict__ sr, const float* __restrict__ srema,
    const float* __restrict__ hr, float* __restrict__ p_sum,
    float* __restrict__ p_sum2, float* __restrict__ p_loss) {
  const int tid = threadIdx.x;
  const int lane = tid & 63;
  const int region = blockIdx.x * 4 + (tid >> 6);
  const int b = region >> 7;
  const int rem = region & 127;
  const int w0 = (rem & 1) << 8;         // 0 or 256
  const int h0 = (rem >> 1) * STRIP;     // 0..504

  const float* __restrict__ srb = sr + (size_t)b * CHW;
  const float* __restrict__ hrb = hr + (size_t)b * CHW;
  const float* __restrict__ emb = srema + (size_t)b * CHW;

  const int col = w0 + 4 * lane;
  const int wl = (w0 == 0) ? 1 : w0 - 1;
  const int wrr = (w0 + 256 >= WW) ? (2 * WW - 2 - (w0 + 256)) : (w0 + 256);
  const bool edge_lane = (lane == 0) || (lane == 63);
  const int wedge = (lane == 0) ? wl : wrr;

  Row A = load_row<false>(hrb, srb, emb, h0 - 1, col, wedge, edge_lane, lane);
  Row B = load_row<true>(hrb, srb, emb, h0, col, wedge, edge_lane, lane);
  Row C = load_row<true>(hrb, srb, emb, h0 + 1, col, wedge, edge_lane, lane);

  float v1 = 0.f, v2 = 0.f, v3 = 0.f;
#pragma unroll
  for (int i = 0; i < STRIP; ++i) {
    Row D = C;  // placeholder for last iteration
    if (i + 2 < STRIP) {
      D = load_row<true>(hrb, srb, emb, h0 + i + 2, col, wedge, edge_lane, lane);
    } else if (i + 2 == STRIP) {
      D = load_row<false>(hrb, srb, emb, h0 + i + 2, col, wedge, edge_lane, lane);
    }

    float vA[6], vB[6], vC[6];
    row6(A, vA); row6(B, vB); row6(C, vC);
    float cs[6], cq[6];
#pragma unroll
    for (int j = 0; j < 6; ++j) {
      cs[j] = vA[j] + vB[j] + vC[j];
      cq[j] = vA[j] * vA[j] + vB[j] * vB[j] + vC[j] * vC[j];
    }
    const float rcv[4] = {B.r.x, B.r.y, B.r.z, B.r.w};
    const float ev[4] = {B.e.x, B.e.y, B.e.z, B.e.w};
#pragma unroll
    for (int c = 0; c < 4; ++c) {
      float s = cs[c] + cs[c + 1] + cs[c + 2];
      float q = cq[c] + cq[c + 1] + cq[c + 2];
      float pvar = (q - s * s / 9.0f) / 8.0f;
      float rc = rcv[c];
      v1 += rc;
      v2 += rc * rc;
      if (rc >= ev[c]) v3 += pvar * (255.0f * rc);
    }
    A = B; B = C; C = D;
  }

  // wave reduce -> one partial per region
#pragma unroll
  for (int off = 32; off > 0; off >>= 1) {
    v1 += __shfl_down(v1, off, 64);
    v2 += __shfl_down(v2, off, 64);
    v3 += __shfl_down(v3, off, 64);
  }
  if (lane == 0) {
    p_sum[region] = v1;
    p_sum2[region] = v2;
    p_loss[region] = v3;
  }
}

// One 1024-thread block: wave b folds batch b's 128 region partials.
__global__ __launch_bounds__(1024) void wl1_reduce(
    const float* __restrict__ p_sum, const float* __restrict__ p_sum2,
    const float* __restrict__ p_loss, float* __restrict__ out) {
  const int tid = threadIdx.x;
  const int b = tid >> 6, k = tid & 63;
  double s = 0.0, s2 = 0.0, sl = 0.0;
#pragma unroll
  for (int j = 0; j < REG_PER_B; j += 64) {
    int i = b * REG_PER_B + j + k;
    s += (double)p_sum[i];
    s2 += (double)p_sum2[i];
    sl += (double)p_loss[i];
  }
#pragma unroll
  for (int off = 32; off > 0; off >>= 1) {
    s += __shfl_down(s, off, 64);
    s2 += __shfl_down(s2, off, 64);
    sl += __shfl_down(sl, off, 64);
  }
  __shared__ double acc[BB];
  if (k == 0) {
    const double n = (double)HW;
    double var = (s2 - s * s / n) / (n - 1.0);
    acc[b] = pow(var, 0.2) * sl;
  }
  __syncthreads();
  if (tid == 0) {
    double tot = 0.0;
#pragma unroll
    for (int j = 0; j < BB; ++j) tot += acc[j];
    out[0] = (float)(tot / (double)((size_t)BB * CHW));
  }
}

extern "C" void kernel_launch(void* const* d_in, const int* in_sizes, int n_in,
                              void* d_out, int out_size, void* d_ws,
                              size_t ws_size, hipStream_t stream) {
  const float* sr = (const float*)d_in[0];
  const float* srema = (const float*)d_in[1];
  const float* hr = (const float*)d_in[2];
  float* out = (float*)d_out;

  float* p_sum = (float*)d_ws;
  float* p_sum2 = p_sum + NREGIONS;
  float* p_loss = p_sum2 + NREGIONS;

  wl1_main<<<NBLOCKS, 256, 0, stream>>>(sr, srema, hr, p_sum, p_sum2, p_loss);
  wl1_reduce<<<1, 1024, 0, stream>>>(p_sum, p_sum2, p_loss, out);
}

// Round 4
// 163.690 us; speedup vs baseline: 1.0596x; 1.0596x over previous
//
#include <hip/hip_runtime.h>
#include <math.h>

// WL1 loss over [B=16, C=3, H=512, W=512] fp32.
//   r = sum_c|hr-sr|/255 ; e = sum_c|hr-ema|/255
//   patch_w[b] = (unbiased var of r over sample)^0.2
//   pixel_w = unbiased 3x3 local var of r (reflect pad)
//   loss = mean(|w*sr - w*hr|) = (1/N) sum patch_w * pixel_w * mask * 255*r
//
// R4: full-width tiles for max residency. Block = 512 cols x 4 center rows,
// 256 threads, 2048 blocks = 8 blocks/CU resident (LDS exactly 20 KB/block).
// Stage A: fill 6-row r-tile + 4-row premasked f-tile (f = mask*255*r), so
// ema/hr are read exactly once and stage B is pure LDS (overlaps other
// blocks' global phases). No inter-block column halo (full-width tile).

#define BB 16
#define HH 512
#define WW 512
#define HW (HH * WW)
#define CHW (3 * HW)
#define STRIPS 128                 // 512 rows / 4
#define NBLOCKS (BB * STRIPS)      // 2048
#define NREGIONS NBLOCKS
#define REG_PER_B STRIPS

__device__ __forceinline__ int reflect_h(int gh) {
  gh = gh < 0 ? -gh : gh;
  return gh >= HH ? 2 * HH - 2 - gh : gh;
}

__global__ __launch_bounds__(256, 8) void wl1_main(
    const float* __restrict__ sr, const float* __restrict__ srema,
    const float* __restrict__ hr, float* __restrict__ p_sum,
    float* __restrict__ p_sum2, float* __restrict__ p_loss) {
  __shared__ float rt[6][WW];  // r for halo rows h0-1 .. h0+4
  __shared__ float ft[4][WW];  // premasked 255*r for center rows h0 .. h0+3
  const int tid = threadIdx.x;
  const int bid = blockIdx.x;
  const int b = bid >> 7;
  const int h0 = (bid & 127) << 2;
  const float* __restrict__ srb = sr + (size_t)b * CHW;
  const float* __restrict__ hrb = hr + (size_t)b * CHW;
  const float* __restrict__ emb = srema + (size_t)b * CHW;

  // Stage A: 6 halo rows x 128 float4-groups = 768 items, 3 clean passes.
#pragma unroll
  for (int it = 0; it < 3; ++it) {
    const int item = it * 256 + tid;
    const int row = item >> 7;  // 0..5 (wave-uniform)
    const int g = item & 127;
    const int gh = reflect_h(h0 - 1 + row);
    const float* hp = hrb + gh * WW + 4 * g;
    const float* sp = srb + gh * WW + 4 * g;
    float4 h0v = *(const float4*)hp;
    float4 h1v = *(const float4*)(hp + HW);
    float4 h2v = *(const float4*)(hp + 2 * HW);
    float4 s0v = *(const float4*)sp;
    float4 s1v = *(const float4*)(sp + HW);
    float4 s2v = *(const float4*)(sp + 2 * HW);
    float4 r4;
    r4.x = (fabsf(h0v.x - s0v.x) + fabsf(h1v.x - s1v.x) + fabsf(h2v.x - s2v.x)) / 255.0f;
    r4.y = (fabsf(h0v.y - s0v.y) + fabsf(h1v.y - s1v.y) + fabsf(h2v.y - s2v.y)) / 255.0f;
    r4.z = (fabsf(h0v.z - s0v.z) + fabsf(h1v.z - s1v.z) + fabsf(h2v.z - s2v.z)) / 255.0f;
    r4.w = (fabsf(h0v.w - s0v.w) + fabsf(h1v.w - s1v.w) + fabsf(h2v.w - s2v.w)) / 255.0f;
    *(float4*)&rt[row][4 * g] = r4;
    if (row >= 1 && row <= 4) {  // center row: also compute premasked factor
      const float* ep = emb + gh * WW + 4 * g;
      float4 e0v = *(const float4*)ep;
      float4 e1v = *(const float4*)(ep + HW);
      float4 e2v = *(const float4*)(ep + 2 * HW);
      float4 e4, f4;
      e4.x = (fabsf(h0v.x - e0v.x) + fabsf(h1v.x - e1v.x) + fabsf(h2v.x - e2v.x)) / 255.0f;
      e4.y = (fabsf(h0v.y - e0v.y) + fabsf(h1v.y - e1v.y) + fabsf(h2v.y - e2v.y)) / 255.0f;
      e4.z = (fabsf(h0v.z - e0v.z) + fabsf(h1v.z - e1v.z) + fabsf(h2v.z - e2v.z)) / 255.0f;
      e4.w = (fabsf(h0v.w - e0v.w) + fabsf(h1v.w - e1v.w) + fabsf(h2v.w - e2v.w)) / 255.0f;
      f4.x = (r4.x >= e4.x) ? 255.0f * r4.x : 0.0f;
      f4.y = (r4.y >= e4.y) ? 255.0f * r4.y : 0.0f;
      f4.z = (r4.z >= e4.z) ? 255.0f * r4.z : 0.0f;
      f4.w = (r4.w >= e4.w) ? 255.0f * r4.w : 0.0f;
      *(float4*)&ft[row - 1][4 * g] = f4;
    }
  }
  __syncthreads();

  // Stage B: pure LDS. Thread -> output rows {r0, r0+2}, float4 group g.
  const int g = tid & 127;
  const int r0 = tid >> 7;  // 0 or 1
  const int li = (g == 0) ? 1 : 4 * g - 1;
  const int ri = (g == 127) ? 510 : 4 * g + 4;
  float v1 = 0.f, v2 = 0.f, v3 = 0.f;
#pragma unroll
  for (int k = 0; k < 2; ++k) {
    const int orow = r0 + 2 * k;  // output row within strip (0..3)
    float cs[6] = {0, 0, 0, 0, 0, 0}, cq[6] = {0, 0, 0, 0, 0, 0};
    float center[4];
#pragma unroll
    for (int dr = 0; dr < 3; ++dr) {
      const int row = orow + dr;
      float4 c4 = *(const float4*)&rt[row][4 * g];
      float lv = rt[row][li];
      float rv = rt[row][ri];
      float v[6] = {lv, c4.x, c4.y, c4.z, c4.w, rv};
#pragma unroll
      for (int j = 0; j < 6; ++j) {
        cs[j] += v[j];
        cq[j] += v[j] * v[j];
      }
      if (dr == 1) { center[0] = c4.x; center[1] = c4.y; center[2] = c4.z; center[3] = c4.w; }
    }
    float4 f4 = *(const float4*)&ft[orow][4 * g];
    const float fv[4] = {f4.x, f4.y, f4.z, f4.w};
#pragma unroll
    for (int c = 0; c < 4; ++c) {
      float s = cs[c] + cs[c + 1] + cs[c + 2];
      float q = cq[c] + cq[c + 1] + cq[c + 2];
      float pvar = (q - s * s / 9.0f) / 8.0f;
      float rc = center[c];
      v1 += rc;
      v2 += rc * rc;
      v3 += pvar * fv[c];
    }
  }

  // Reduce: wave shuffle, then cross-wave via reused LDS (after barrier).
#pragma unroll
  for (int off = 32; off > 0; off >>= 1) {
    v1 += __shfl_down(v1, off, 64);
    v2 += __shfl_down(v2, off, 64);
    v3 += __shfl_down(v3, off, 64);
  }
  __syncthreads();  // all stage-B LDS reads done before reuse
  const int wave = tid >> 6, lane = tid & 63;
  if (lane == 0) {
    rt[0][wave] = v1;
    rt[0][8 + wave] = v2;
    rt[0][16 + wave] = v3;
  }
  __syncthreads();
  if (tid == 0) {
    p_sum[bid] = rt[0][0] + rt[0][1] + rt[0][2] + rt[0][3];
    p_sum2[bid] = rt[0][8] + rt[0][9] + rt[0][10] + rt[0][11];
    p_loss[bid] = rt[0][16] + rt[0][17] + rt[0][18] + rt[0][19];
  }
}

// One 1024-thread block: wave b folds batch b's 128 strip partials.
__global__ __launch_bounds__(1024) void wl1_reduce(
    const float* __restrict__ p_sum, const float* __restrict__ p_sum2,
    const float* __restrict__ p_loss, float* __restrict__ out) {
  const int tid = threadIdx.x;
  const int b = tid >> 6, k = tid & 63;
  double s = 0.0, s2 = 0.0, sl = 0.0;
#pragma unroll
  for (int j = 0; j < REG_PER_B; j += 64) {
    int i = b * REG_PER_B + j + k;
    s += (double)p_sum[i];
    s2 += (double)p_sum2[i];
    sl += (double)p_loss[i];
  }
#pragma unroll
  for (int off = 32; off > 0; off >>= 1) {
    s += __shfl_down(s, off, 64);
    s2 += __shfl_down(s2, off, 64);
    sl += __shfl_down(sl, off, 64);
  }
  __shared__ double acc[BB];
  if (k == 0) {
    const double n = (double)HW;
    double var = (s2 - s * s / n) / (n - 1.0);
    acc[b] = pow(var, 0.2) * sl;
  }
  __syncthreads();
  if (tid == 0) {
    double tot = 0.0;
#pragma unroll
    for (int j = 0; j < BB; ++j) tot += acc[j];
    out[0] = (float)(tot / (double)((size_t)BB * CHW));
  }
}

extern "C" void kernel_launch(void* const* d_in, const int* in_sizes, int n_in,
                              void* d_out, int out_size, void* d_ws,
                              size_t ws_size, hipStream_t stream) {
  const float* sr = (const float*)d_in[0];
  const float* srema = (const float*)d_in[1];
  const float* hr = (const float*)d_in[2];
  float* out = (float*)d_out;

  float* p_sum = (float*)d_ws;
  float* p_sum2 = p_sum + NREGIONS;
  float* p_loss = p_sum2 + NREGIONS;

  wl1_main<<<NBLOCKS, 256, 0, stream>>>(sr, srema, hr, p_sum, p_sum2, p_loss);
  wl1_reduce<<<1, 1024, 0, stream>>>(p_sum, p_sum2, p_loss, out);
}